// Round 8
// baseline (49.903 us; speedup 1.0000x reference)
//
#include <hip/hip_runtime.h>
#include <hip/hip_bf16.h>

// YOLO layer decode: x (16, 340, 76, 76) f32 -> out (16, 4*76*76, 85) f32.
// One (b,a,y) slab per block: transpose [c=85][x=76] -> [x=76][c=85] via LDS.
// This round's single variable vs round 7: NONTEMPORAL output stores, so the
// 112 MB write stream doesn't evict the (L3-resident, 125.6 MB) input.

constexpr int BS = 16;
constexpr int NA = 4;
constexpr int NC = 85;
constexpr int FY = 76;
constexpr int FX = 76;
constexpr int PLANE = FY * FX;        // 5776
constexpr int TILE  = NC * FX;        // 6460 floats per slab
constexpr int RV    = FX / 4;         // 19 float4s per row
constexpr int NV    = NC * RV;        // 1615 float4s per slab
constexpr int NTHR  = 512;
constexpr int FULL  = 3 * NTHR;       // 1536 vectors covered by k=0..2
constexpr int TAIL  = NV - FULL;      // 79 vectors, threads 0..78
constexpr float STRIDE_F = 8.0f;
constexpr float LOG2E = 1.4426950408889634f;

typedef float f32x4 __attribute__((ext_vector_type(4)));

__device__ __forceinline__ float fast_sigmoid(float v) {
    return __builtin_amdgcn_rcpf(1.0f + __builtin_amdgcn_exp2f(v * -LOG2E));
}
__device__ __forceinline__ float fast_exp(float v) {
    return __builtin_amdgcn_exp2f(v * LOG2E);
}

__global__ __launch_bounds__(NTHR)
void yolo_decode_kernel(const float* __restrict__ x,
                        const float* __restrict__ anchors,
                        float* __restrict__ out) {
    __shared__ float lds[TILE];       // [x][c], flat: x*NC + c  (25840 B)

    const int blk = blockIdx.x;       // (b*NA + a)*FY + y
    const int y   = blk % FY;
    const int ba  = blk / FY;
    const int a   = ba % NA;

    const float ax = anchors[a * 2 + 0] * STRIDE_F;
    const float ay = anchors[a * 2 + 1] * STRIDE_F;
    const float yf = (float)y;

    const float* __restrict__ inbase = x + (size_t)ba * NC * PLANE + (size_t)y * FX;
    const int t = threadIdx.x;

    // --- Load phase: issue all loads back-to-back (maximize vmcnt depth). ---
    float4 v[4];
    #pragma unroll
    for (int k = 0; k < 3; ++k) {
        const int i = t + NTHR * k;           // < 1536
        const int c = i / RV;                 // magic-mul
        const int j = i - c * RV;
        v[k] = *(const float4*)(inbase + (size_t)c * PLANE + j * 4);
    }
    if (t < TAIL) {
        const int i = FULL + t;
        const int c = i / RV;
        const int j = i - c * RV;
        v[3] = *(const float4*)(inbase + (size_t)c * PLANE + j * 4);
    }

    // --- Transform + LDS scatter (stride-85 rows). ---
    #pragma unroll
    for (int k = 0; k < 4; ++k) {
        if (k < 3 || t < TAIL) {
            const int i = (k < 3) ? (t + NTHR * k) : (FULL + t);
            const int c = i / RV;
            const int j = i - c * RV;
            const float vv[4] = {v[k].x, v[k].y, v[k].z, v[k].w};
            float* __restrict__ dst = &lds[(4 * j) * NC + c];
            if (c >= 4) {
                #pragma unroll
                for (int kk = 0; kk < 4; ++kk)
                    dst[kk * NC] = fast_sigmoid(vv[kk]);
            } else if (c == 0) {
                #pragma unroll
                for (int kk = 0; kk < 4; ++kk)
                    dst[kk * NC] = fast_sigmoid(vv[kk]) * STRIDE_F
                                 + (float)(4 * j + kk) * STRIDE_F;
            } else if (c == 1) {
                #pragma unroll
                for (int kk = 0; kk < 4; ++kk)
                    dst[kk * NC] = fast_sigmoid(vv[kk]) * STRIDE_F + yf * STRIDE_F;
            } else if (c == 2) {
                #pragma unroll
                for (int kk = 0; kk < 4; ++kk)
                    dst[kk * NC] = fast_exp(vv[kk]) * ax;
            } else {
                #pragma unroll
                for (int kk = 0; kk < 4; ++kk)
                    dst[kk * NC] = fast_exp(vv[kk]) * ay;
            }
        }
    }

    __syncthreads();

    // --- Store: contiguous 6460 floats (1615 float4s), nontemporal. ---
    const f32x4* __restrict__ ldsv = (const f32x4*)lds;
    f32x4* __restrict__ ov = (f32x4*)(out + (size_t)blk * TILE);
    #pragma unroll
    for (int k = 0; k < 3; ++k)
        __builtin_nontemporal_store(ldsv[t + NTHR * k], &ov[t + NTHR * k]);
    if (t < TAIL)
        __builtin_nontemporal_store(ldsv[FULL + t], &ov[FULL + t]);
}

extern "C" void kernel_launch(void* const* d_in, const int* in_sizes, int n_in,
                              void* d_out, int out_size, void* d_ws, size_t ws_size,
                              hipStream_t stream) {
    const float* x       = (const float*)d_in[0];
    const float* anchors = (const float*)d_in[1];
    float* out           = (float*)d_out;

    const int nblocks = BS * NA * FY;   // 4864
    yolo_decode_kernel<<<nblocks, NTHR, 0, stream>>>(x, anchors, out);
}

// Round 9
// 49.455 us; speedup vs baseline: 1.0090x; 1.0090x over previous
//
#include <hip/hip_runtime.h>
#include <hip/hip_bf16.h>

// YOLO layer decode: x (16, 340, 76, 76) f32 -> out (16, 4*76*76, 85) f32.
// One (b,a,y) slab per block: transpose [c=85][x=76] -> [x=76][c=85] via LDS.
// Single variable vs round 7: an asm scheduling fence between the load phase
// and the transform phase, so the 3-4 global_load_dwordx4 per thread are
// issued back-to-back (true MLP). Round 7 compiled to VGPR=16 => loads were
// re-sunk next to their uses and serialized on latency.

constexpr int BS = 16;
constexpr int NA = 4;
constexpr int NC = 85;
constexpr int FY = 76;
constexpr int FX = 76;
constexpr int PLANE = FY * FX;        // 5776
constexpr int TILE  = NC * FX;        // 6460 floats per slab
constexpr int RV    = FX / 4;         // 19 float4s per row
constexpr int NV    = NC * RV;        // 1615 float4s per slab
constexpr int NTHR  = 512;
constexpr int FULL  = 3 * NTHR;       // 1536 vectors covered by k=0..2
constexpr int TAIL  = NV - FULL;      // 79 vectors, threads 0..78
constexpr float STRIDE_F = 8.0f;
constexpr float LOG2E = 1.4426950408889634f;

__device__ __forceinline__ float fast_sigmoid(float v) {
    return __builtin_amdgcn_rcpf(1.0f + __builtin_amdgcn_exp2f(v * -LOG2E));
}
__device__ __forceinline__ float fast_exp(float v) {
    return __builtin_amdgcn_exp2f(v * LOG2E);
}

// Transform one float4 from channel-row c at quad j, scatter to lds[x][c].
__device__ __forceinline__ void xform_scatter(float* __restrict__ lds,
                                              int c, int j, float4 v,
                                              float ax, float ay, float yf) {
    const float vv[4] = {v.x, v.y, v.z, v.w};
    float* __restrict__ dst = &lds[(4 * j) * NC + c];
    if (c >= 4) {
        #pragma unroll
        for (int kk = 0; kk < 4; ++kk)
            dst[kk * NC] = fast_sigmoid(vv[kk]);
    } else if (c == 0) {
        #pragma unroll
        for (int kk = 0; kk < 4; ++kk)
            dst[kk * NC] = fast_sigmoid(vv[kk]) * STRIDE_F
                         + (float)(4 * j + kk) * STRIDE_F;
    } else if (c == 1) {
        #pragma unroll
        for (int kk = 0; kk < 4; ++kk)
            dst[kk * NC] = fast_sigmoid(vv[kk]) * STRIDE_F + yf * STRIDE_F;
    } else if (c == 2) {
        #pragma unroll
        for (int kk = 0; kk < 4; ++kk)
            dst[kk * NC] = fast_exp(vv[kk]) * ax;
    } else {
        #pragma unroll
        for (int kk = 0; kk < 4; ++kk)
            dst[kk * NC] = fast_exp(vv[kk]) * ay;
    }
}

__global__ __launch_bounds__(NTHR)
void yolo_decode_kernel(const float* __restrict__ x,
                        const float* __restrict__ anchors,
                        float* __restrict__ out) {
    __shared__ float lds[TILE];       // [x][c], flat: x*NC + c  (25840 B)

    const int blk = blockIdx.x;       // (b*NA + a)*FY + y
    const int y   = blk % FY;
    const int ba  = blk / FY;
    const int a   = ba % NA;

    const float ax = anchors[a * 2 + 0] * STRIDE_F;
    const float ay = anchors[a * 2 + 1] * STRIDE_F;
    const float yf = (float)y;

    const float* __restrict__ inbase = x + (size_t)ba * NC * PLANE + (size_t)y * FX;
    const int t = threadIdx.x;

    // --- Addresses first, then all loads back-to-back. ---
    const int i0 = t,            c0 = i0 / RV, j0 = i0 - c0 * RV;
    const int i1 = t + NTHR,     c1 = i1 / RV, j1 = i1 - c1 * RV;
    const int i2 = t + 2 * NTHR, c2 = i2 / RV, j2 = i2 - c2 * RV;
    const int i3 = FULL + t,     c3 = i3 / RV, j3 = i3 - c3 * RV;

    const float4 v0 = *(const float4*)(inbase + (size_t)c0 * PLANE + j0 * 4);
    const float4 v1 = *(const float4*)(inbase + (size_t)c1 * PLANE + j1 * 4);
    const float4 v2 = *(const float4*)(inbase + (size_t)c2 * PLANE + j2 * 4);
    float4 v3 = {};
    if (t < TAIL)
        v3 = *(const float4*)(inbase + (size_t)c3 * PLANE + j3 * 4);

    // Scheduling fence: loads may not sink below this point -> all 3-4 are
    // in flight before the first transform consumes v0.
    asm volatile("" ::: "memory");

    // --- Transform + LDS scatter (stride-85 rows, 8-way struct. conflict). ---
    xform_scatter(lds, c0, j0, v0, ax, ay, yf);
    xform_scatter(lds, c1, j1, v1, ax, ay, yf);
    xform_scatter(lds, c2, j2, v2, ax, ay, yf);
    if (t < TAIL)
        xform_scatter(lds, c3, j3, v3, ax, ay, yf);

    __syncthreads();

    // --- Store: contiguous 6460 floats (1615 float4s), 16B-aligned base. ---
    const float4* __restrict__ ldsv = (const float4*)lds;
    float4* __restrict__ ov = (float4*)(out + (size_t)blk * TILE);
    #pragma unroll
    for (int k = 0; k < 3; ++k)
        ov[t + NTHR * k] = ldsv[t + NTHR * k];
    if (t < TAIL)
        ov[FULL + t] = ldsv[FULL + t];
}

extern "C" void kernel_launch(void* const* d_in, const int* in_sizes, int n_in,
                              void* d_out, int out_size, void* d_ws, size_t ws_size,
                              hipStream_t stream) {
    const float* x       = (const float*)d_in[0];
    const float* anchors = (const float*)d_in[1];
    float* out           = (float*)d_out;

    const int nblocks = BS * NA * FY;   // 4864
    yolo_decode_kernel<<<nblocks, NTHR, 0, stream>>>(x, anchors, out);
}

// Round 10
// 41.106 us; speedup vs baseline: 1.2140x; 1.2031x over previous
//
#include <hip/hip_runtime.h>
#include <hip/hip_bf16.h>

// YOLO layer decode: x (16, 340, 76, 76) f32 -> out (16, 4*76*76, 85) f32.
// This round: 2 y-rows per block (608B read chunks, 51.7KB contiguous store
// run, 51.7KB LDS -> 3 blocks/CU) + bijective chunked XCD swizzle so blocks
// sharing cache lines / DRAM pages (same ba, adjacent y) stay on one XCD L2.

constexpr int BS = 16;
constexpr int NA = 4;
constexpr int NC = 85;
constexpr int FY = 76;
constexpr int FX = 76;
constexpr int PLANE = FY * FX;        // 5776
constexpr int TILE  = NC * FX;        // 6460 floats per slab (one y)
constexpr int YG    = 2;              // y rows per block
constexpr int CHUNK = YG * FX;        // 152 floats contiguous per channel
constexpr int RVC   = CHUNK / 4;      // 38 float4s per channel chunk
constexpr int NV2   = NC * RVC;       // 3230 float4s per block
constexpr int NTHR  = 512;
constexpr int KFULL = NV2 / NTHR;     // 6 full passes
constexpr int TAIL2 = NV2 - KFULL * NTHR;   // 158 (threads 0..157)
constexpr int NBLK  = BS * NA * (FY / YG);  // 2432
constexpr int PER_XCD = NBLK / 8;     // 304 = 8 ba-panels x 38 ypairs
constexpr float STRIDE_F = 8.0f;
constexpr float LOG2E = 1.4426950408889634f;

__device__ __forceinline__ float fast_sigmoid(float v) {
    return __builtin_amdgcn_rcpf(1.0f + __builtin_amdgcn_exp2f(v * -LOG2E));
}
__device__ __forceinline__ float fast_exp(float v) {
    return __builtin_amdgcn_exp2f(v * LOG2E);
}

// Transform one float4 of channel c at quad j (j in [0,38)), scatter to
// lds[pos][c] where pos = 4j..4j+3 spans the 2-row x-range.
__device__ __forceinline__ void xform_scatter(float* __restrict__ lds,
                                              int c, int j, float4 v,
                                              float ax, float ay, float y0f) {
    const float vv[4] = {v.x, v.y, v.z, v.w};
    const int pos0 = 4 * j;
    const int ylocal = (j >= RVC / 2) ? 1 : 0;   // 76/4=19: quad never straddles rows
    const int xi0 = pos0 - ylocal * FX;
    float* __restrict__ dst = &lds[pos0 * NC + c];
    if (c >= 4) {
        #pragma unroll
        for (int kk = 0; kk < 4; ++kk)
            dst[kk * NC] = fast_sigmoid(vv[kk]);
    } else if (c == 0) {
        #pragma unroll
        for (int kk = 0; kk < 4; ++kk)
            dst[kk * NC] = fast_sigmoid(vv[kk]) * STRIDE_F
                         + (float)(xi0 + kk) * STRIDE_F;
    } else if (c == 1) {
        const float yf = y0f + (float)ylocal;
        #pragma unroll
        for (int kk = 0; kk < 4; ++kk)
            dst[kk * NC] = fast_sigmoid(vv[kk]) * STRIDE_F + yf * STRIDE_F;
    } else if (c == 2) {
        #pragma unroll
        for (int kk = 0; kk < 4; ++kk)
            dst[kk * NC] = fast_exp(vv[kk]) * ax;
    } else {
        #pragma unroll
        for (int kk = 0; kk < 4; ++kk)
            dst[kk * NC] = fast_exp(vv[kk]) * ay;
    }
}

__global__ __launch_bounds__(NTHR)
void yolo_decode_kernel(const float* __restrict__ x,
                        const float* __restrict__ anchors,
                        float* __restrict__ out) {
    __shared__ float lds[NC * CHUNK];   // 12920 floats = 51680 B

    // Bijective chunked XCD swizzle: XCD k (= blockIdx%8 round-robin) gets
    // orig in [k*304,(k+1)*304) = 8 whole ba panels, y-pairs in order.
    const int B    = blockIdx.x;
    const int orig = (B & 7) * PER_XCD + (B >> 3);
    const int yp   = orig % (FY / YG);
    const int ba   = orig / (FY / YG);
    const int a    = ba % NA;

    const float ax  = anchors[a * 2 + 0] * STRIDE_F;
    const float ay  = anchors[a * 2 + 1] * STRIDE_F;
    const float y0f = (float)(YG * yp);

    const float* __restrict__ inbase = x + (size_t)ba * NC * PLANE + (size_t)yp * CHUNK;
    const int t = threadIdx.x;

    // --- Load phase: issue all 6-7 loads back-to-back. ---
    float4 v[KFULL + 1];
    #pragma unroll
    for (int k = 0; k < KFULL; ++k) {
        const int i = t + NTHR * k;
        const int c = i / RVC;            // magic-mul
        const int j = i - c * RVC;
        v[k] = *(const float4*)(inbase + (size_t)c * PLANE + j * 4);
    }
    if (t < TAIL2) {
        const int i = KFULL * NTHR + t;
        const int c = i / RVC;
        const int j = i - c * RVC;
        v[KFULL] = *(const float4*)(inbase + (size_t)c * PLANE + j * 4);
    }

    asm volatile("" ::: "memory");   // keep loads grouped above the transforms

    // --- Transform + LDS scatter. ---
    #pragma unroll
    for (int k = 0; k < KFULL; ++k) {
        const int i = t + NTHR * k;
        const int c = i / RVC;
        const int j = i - c * RVC;
        xform_scatter(lds, c, j, v[k], ax, ay, y0f);
    }
    if (t < TAIL2) {
        const int i = KFULL * NTHR + t;
        const int c = i / RVC;
        const int j = i - c * RVC;
        xform_scatter(lds, c, j, v[KFULL], ax, ay, y0f);
    }

    __syncthreads();

    // --- Store: 2 slabs = 12920 contiguous floats (3230 float4s). ---
    const float4* __restrict__ ldsv = (const float4*)lds;
    float4* __restrict__ ov = (float4*)(out + (size_t)(ba * FY + YG * yp) * TILE);
    #pragma unroll
    for (int k = 0; k < KFULL; ++k)
        ov[t + NTHR * k] = ldsv[t + NTHR * k];
    if (t < TAIL2)
        ov[KFULL * NTHR + t] = ldsv[KFULL * NTHR + t];
}

extern "C" void kernel_launch(void* const* d_in, const int* in_sizes, int n_in,
                              void* d_out, int out_size, void* d_ws, size_t ws_size,
                              hipStream_t stream) {
    const float* x       = (const float*)d_in[0];
    const float* anchors = (const float*)d_in[1];
    float* out           = (float*)d_out;

    yolo_decode_kernel<<<NBLK, NTHR, 0, stream>>>(x, anchors, out);
}

// Round 11
// 40.860 us; speedup vs baseline: 1.2213x; 1.0060x over previous
//
#include <hip/hip_runtime.h>
#include <hip/hip_bf16.h>

// YOLO layer decode: x (16, 340, 76, 76) f32 -> out (16, 4*76*76, 85) f32.
// 2 y-rows per block (608B read chunks, 51.7KB contiguous store run) +
// bijective chunked XCD swizzle (blocks sharing lines/pages stay on one XCD).
// This round's single variable: 1024 threads/block -> 2 blocks/CU x 16 waves
// = 32 waves/CU (100% wave cap; was 24 at 512 threads).

constexpr int BS = 16;
constexpr int NA = 4;
constexpr int NC = 85;
constexpr int FY = 76;
constexpr int FX = 76;
constexpr int PLANE = FY * FX;        // 5776
constexpr int TILE  = NC * FX;        // 6460 floats per slab (one y)
constexpr int YG    = 2;              // y rows per block
constexpr int CHUNK = YG * FX;        // 152 floats contiguous per channel
constexpr int RVC   = CHUNK / 4;      // 38 float4s per channel chunk
constexpr int NV2   = NC * RVC;       // 3230 float4s per block
constexpr int NTHR  = 1024;
constexpr int KFULL = NV2 / NTHR;     // 3 full passes
constexpr int TAIL2 = NV2 - KFULL * NTHR;   // 158 (threads 0..157)
constexpr int NBLK  = BS * NA * (FY / YG);  // 2432
constexpr int PER_XCD = NBLK / 8;     // 304 = 8 ba-panels x 38 ypairs
constexpr float STRIDE_F = 8.0f;
constexpr float LOG2E = 1.4426950408889634f;

__device__ __forceinline__ float fast_sigmoid(float v) {
    return __builtin_amdgcn_rcpf(1.0f + __builtin_amdgcn_exp2f(v * -LOG2E));
}
__device__ __forceinline__ float fast_exp(float v) {
    return __builtin_amdgcn_exp2f(v * LOG2E);
}

// Transform one float4 of channel c at quad j (j in [0,38)), scatter to
// lds[pos][c] where pos = 4j..4j+3 spans the 2-row x-range.
__device__ __forceinline__ void xform_scatter(float* __restrict__ lds,
                                              int c, int j, float4 v,
                                              float ax, float ay, float y0f) {
    const float vv[4] = {v.x, v.y, v.z, v.w};
    const int pos0 = 4 * j;
    const int ylocal = (j >= RVC / 2) ? 1 : 0;   // 76/4=19: quad never straddles rows
    const int xi0 = pos0 - ylocal * FX;
    float* __restrict__ dst = &lds[pos0 * NC + c];
    if (c >= 4) {
        #pragma unroll
        for (int kk = 0; kk < 4; ++kk)
            dst[kk * NC] = fast_sigmoid(vv[kk]);
    } else if (c == 0) {
        #pragma unroll
        for (int kk = 0; kk < 4; ++kk)
            dst[kk * NC] = fast_sigmoid(vv[kk]) * STRIDE_F
                         + (float)(xi0 + kk) * STRIDE_F;
    } else if (c == 1) {
        const float yf = y0f + (float)ylocal;
        #pragma unroll
        for (int kk = 0; kk < 4; ++kk)
            dst[kk * NC] = fast_sigmoid(vv[kk]) * STRIDE_F + yf * STRIDE_F;
    } else if (c == 2) {
        #pragma unroll
        for (int kk = 0; kk < 4; ++kk)
            dst[kk * NC] = fast_exp(vv[kk]) * ax;
    } else {
        #pragma unroll
        for (int kk = 0; kk < 4; ++kk)
            dst[kk * NC] = fast_exp(vv[kk]) * ay;
    }
}

__global__ __launch_bounds__(NTHR)
void yolo_decode_kernel(const float* __restrict__ x,
                        const float* __restrict__ anchors,
                        float* __restrict__ out) {
    __shared__ float lds[NC * CHUNK];   // 12920 floats = 51680 B

    // Bijective chunked XCD swizzle: XCD k (= blockIdx%8 round-robin) gets
    // orig in [k*304,(k+1)*304) = 8 whole ba panels, y-pairs in order.
    const int B    = blockIdx.x;
    const int orig = (B & 7) * PER_XCD + (B >> 3);
    const int yp   = orig % (FY / YG);
    const int ba   = orig / (FY / YG);
    const int a    = ba % NA;

    const float ax  = anchors[a * 2 + 0] * STRIDE_F;
    const float ay  = anchors[a * 2 + 1] * STRIDE_F;
    const float y0f = (float)(YG * yp);

    const float* __restrict__ inbase = x + (size_t)ba * NC * PLANE + (size_t)yp * CHUNK;
    const int t = threadIdx.x;

    // --- Load phase: issue all 3-4 loads back-to-back. ---
    float4 v[KFULL + 1];
    #pragma unroll
    for (int k = 0; k < KFULL; ++k) {
        const int i = t + NTHR * k;
        const int c = i / RVC;            // magic-mul
        const int j = i - c * RVC;
        v[k] = *(const float4*)(inbase + (size_t)c * PLANE + j * 4);
    }
    if (t < TAIL2) {
        const int i = KFULL * NTHR + t;
        const int c = i / RVC;
        const int j = i - c * RVC;
        v[KFULL] = *(const float4*)(inbase + (size_t)c * PLANE + j * 4);
    }

    asm volatile("" ::: "memory");   // keep loads grouped above the transforms

    // --- Transform + LDS scatter. ---
    #pragma unroll
    for (int k = 0; k < KFULL; ++k) {
        const int i = t + NTHR * k;
        const int c = i / RVC;
        const int j = i - c * RVC;
        xform_scatter(lds, c, j, v[k], ax, ay, y0f);
    }
    if (t < TAIL2) {
        const int i = KFULL * NTHR + t;
        const int c = i / RVC;
        const int j = i - c * RVC;
        xform_scatter(lds, c, j, v[KFULL], ax, ay, y0f);
    }

    __syncthreads();

    // --- Store: 2 slabs = 12920 contiguous floats (3230 float4s). ---
    const float4* __restrict__ ldsv = (const float4*)lds;
    float4* __restrict__ ov = (float4*)(out + (size_t)(ba * FY + YG * yp) * TILE);
    #pragma unroll
    for (int k = 0; k < KFULL; ++k)
        ov[t + NTHR * k] = ldsv[t + NTHR * k];
    if (t < TAIL2)
        ov[KFULL * NTHR + t] = ldsv[KFULL * NTHR + t];
}

extern "C" void kernel_launch(void* const* d_in, const int* in_sizes, int n_in,
                              void* d_out, int out_size, void* d_ws, size_t ws_size,
                              hipStream_t stream) {
    const float* x       = (const float*)d_in[0];
    const float* anchors = (const float*)d_in[1];
    float* out           = (float*)d_out;

    yolo_decode_kernel<<<NBLK, NTHR, 0, stream>>>(x, anchors, out);
}